// Round 1
// baseline (378.793 us; speedup 1.0000x reference)
//
#include <hip/hip_runtime.h>

typedef __attribute__((ext_vector_type(4))) float f32x4;
typedef __attribute__((ext_vector_type(8))) _Float16 f16x8;
typedef __attribute__((ext_vector_type(4))) _Float16 f16x4;

__device__ __forceinline__ void gload_lds16(const void* g, void* l) {
  __builtin_amdgcn_global_load_lds((__attribute__((address_space(1))) void*)(g),
                                   (__attribute__((address_space(3))) void*)(l), 16, 0, 0);
}

// ---------------- cast fp32 -> fp16 ----------------
__global__ __launch_bounds__(256) void cast_f32_f16(const float* __restrict__ x,
                                                    _Float16* __restrict__ y, int n) {
  int i = (blockIdx.x * 256 + threadIdx.x) * 4;
  if (i < n) {
    float4 v = *(const float4*)(x + i);
    f16x4 o = { (_Float16)v.x, (_Float16)v.y, (_Float16)v.z, (_Float16)v.w };
    *(f16x4*)(y + i) = o;
  }
}

// ---- transpose+cast weights: W[2048][2048] f32 (k-major) -> Wt[n][k] f16 ----
__global__ __launch_bounds__(256) void wtrans(const float* __restrict__ W0, const float* __restrict__ W1,
                                              const float* __restrict__ W2, const float* __restrict__ W3,
                                              _Float16* __restrict__ out) {
  const float* W = blockIdx.z == 0 ? W0 : blockIdx.z == 1 ? W1 : blockIdx.z == 2 ? W2 : W3;
  _Float16* Wt = out + (size_t)blockIdx.z * (2048u * 2048u);
  __shared__ _Float16 tile[64][65];  // odd pad -> conflict-light transpose
  const int tid = threadIdx.x;
  const int k0 = blockIdx.y * 64, n0 = blockIdx.x * 64;
  #pragma unroll
  for (int p = 0; p < 4; ++p) {
    int o = p * 256 + tid, r = o >> 4, c = o & 15;
    float4 v = *(const float4*)(W + (size_t)(k0 + r) * 2048 + n0 + c * 4);
    tile[r][c * 4 + 0] = (_Float16)v.x;
    tile[r][c * 4 + 1] = (_Float16)v.y;
    tile[r][c * 4 + 2] = (_Float16)v.z;
    tile[r][c * 4 + 3] = (_Float16)v.w;
  }
  __syncthreads();
  #pragma unroll
  for (int p = 0; p < 2; ++p) {
    int o = p * 256 + tid, nl = o >> 3, c = o & 7;
    f16x8 u;
    #pragma unroll
    for (int i = 0; i < 8; ++i) u[i] = tile[c * 8 + i][nl];
    *(f16x8*)(Wt + (size_t)(n0 + nl) * 2048 + k0 + c * 8) = u;
  }
}

// ---- transpose V[b*2048+s][h*128+d] -> Vt[(b*16+h)*128+d][s] (f16) ----
__global__ __launch_bounds__(256) void vtrans(const _Float16* __restrict__ V, _Float16* __restrict__ Vt) {
  const int s0 = blockIdx.x * 64, d0 = blockIdx.y * 64, bh = blockIdx.z;
  const int b = bh >> 4, h = bh & 15;
  __shared__ _Float16 tile[64][65];
  const int tid = threadIdx.x;
  #pragma unroll
  for (int p = 0; p < 2; ++p) {
    int o = p * 256 + tid, sl = o >> 3, c = o & 7;
    f16x8 v = *(const f16x8*)(V + (size_t)(b * 2048 + s0 + sl) * 2048 + h * 128 + d0 + c * 8);
    #pragma unroll
    for (int i = 0; i < 8; ++i) tile[sl][c * 8 + i] = v[i];
  }
  __syncthreads();
  #pragma unroll
  for (int p = 0; p < 2; ++p) {
    int o = p * 256 + tid, dl = o >> 3, c = o & 7;
    f16x8 u;
    #pragma unroll
    for (int i = 0; i < 8; ++i) u[i] = tile[c * 8 + i][dl];
    *(f16x8*)(Vt + (size_t)(bh * 128 + d0 + dl) * 2048 + s0 + c * 8) = u;
  }
}

// ---- m97-style GEMM: C[M][N] = A[M][K] * Bt[N][K]^T, f16 in, OutT out ----
template <typename OutT>
__global__ __launch_bounds__(256) void gemm_bt(const _Float16* __restrict__ A,
                                               const _Float16* __restrict__ Bt,
                                               OutT* __restrict__ C,
                                               int K, int N, size_t zsB, size_t zsC) {
  Bt += (size_t)blockIdx.z * zsB;
  C  += (size_t)blockIdx.z * zsC;
  __shared__ _Float16 As[128 * 32];
  __shared__ _Float16 Bs[128 * 32];
  const int tid = threadIdx.x;
  const int m0 = blockIdx.y * 128, n0 = blockIdx.x * 128;
  const int lane = tid & 63, w = tid >> 6, l16 = lane & 15, quad = lane >> 4;
  const int wm = (w & 1) * 64, wn = (w >> 1) * 64;
  f32x4 acc[4][4];
  #pragma unroll
  for (int i = 0; i < 4; ++i)
    #pragma unroll
    for (int j = 0; j < 4; ++j) acc[i][j] = (f32x4){0.f, 0.f, 0.f, 0.f};

  const int r0 = tid >> 2, c0 = (tid & 3) * 8;
  for (int k0 = 0; k0 < K; k0 += 32) {
    __syncthreads();
    #pragma unroll
    for (int p = 0; p < 2; ++p) {
      int r = p * 64 + r0;
      gload_lds16(A  + (size_t)(m0 + r) * K + k0 + c0, (char*)As + (p * 256 + tid) * 16);
      gload_lds16(Bt + (size_t)(n0 + r) * K + k0 + c0, (char*)Bs + (p * 256 + tid) * 16);
    }
    __builtin_amdgcn_s_waitcnt(0);
    __syncthreads();
    f16x8 af[4], bfv[4];
    #pragma unroll
    for (int i = 0; i < 4; ++i) af[i]  = *(const f16x8*)(As + (wm + i * 16 + l16) * 32 + quad * 8);
    #pragma unroll
    for (int j = 0; j < 4; ++j) bfv[j] = *(const f16x8*)(Bs + (wn + j * 16 + l16) * 32 + quad * 8);
    #pragma unroll
    for (int i = 0; i < 4; ++i)
      #pragma unroll
      for (int j = 0; j < 4; ++j)
        acc[i][j] = __builtin_amdgcn_mfma_f32_16x16x32_f16(af[i], bfv[j], acc[i][j], 0, 0, 0);
  }
  #pragma unroll
  for (int i = 0; i < 4; ++i) {
    const size_t rb = (size_t)(m0 + wm + i * 16 + quad * 4);
    #pragma unroll
    for (int j = 0; j < 4; ++j) {
      const int col = n0 + wn + j * 16 + l16;
      #pragma unroll
      for (int r = 0; r < 4; ++r) C[(rb + r) * N + col] = (OutT)acc[i][j][r];
    }
  }
}

// ---- block-sparse attention: WG = (qblock, head, batch); computes S^T = K.Q^T,
// softmax per query col, then O^T = V^T.P^T with P^T taken straight from regs ----
__global__ __launch_bounds__(256) void attn(const _Float16* __restrict__ Qg,
                                            const _Float16* __restrict__ Kg,
                                            const _Float16* __restrict__ Vtg,
                                            _Float16* __restrict__ Og) {
  const int qb = blockIdx.x, h = blockIdx.y, b = blockIdx.z;
  __shared__ _Float16 Qs[64 * 128];
  __shared__ _Float16 Ks[64 * 128];
  __shared__ _Float16 Vs[128 * 64];
  const int tid = threadIdx.x;
  const int lane = tid & 63, w = tid >> 6, l16 = lane & 15, quad = lane >> 4;
  const char* QsB = (const char*)Qs;
  const char* KsB = (const char*)Ks;
  const char* VsB = (const char*)Vs;

  // stage Q block (64 q-rows x 128 d), 16B-chunk XOR swizzle (rows are 256B -> bank-aliased otherwise)
  #pragma unroll
  for (int p = 0; p < 4; ++p) {
    int o = p * 256 + tid, r = o >> 4, c = o & 15;
    gload_lds16(Qg + (size_t)(b * 2048 + qb * 64 + r) * 2048 + h * 128 + ((c ^ (r & 15)) * 8),
                (char*)Qs + o * 16);
  }
  __builtin_amdgcn_s_waitcnt(0);
  __syncthreads();
  f16x8 qf[4];  // B-operand: n = qrow = w*16+l16, k = d
  #pragma unroll
  for (int ks = 0; ks < 4; ++ks)
    qf[ks] = *(const f16x8*)(QsB + (w * 16 + l16) * 256 + (((ks * 4 + quad) ^ l16) * 16));

  f32x4 sc[5][4];  // S^T: [key = kt*16 + quad*4 + r][qrow = w*16 + l16]
  #pragma unroll
  for (int jj = 0; jj < 5; ++jj) {
    int j = qb - 2 + jj;
    int jc = j < 0 ? 0 : (j > 31 ? 31 : j);
    __syncthreads();
    #pragma unroll
    for (int p = 0; p < 4; ++p) {
      int o = p * 256 + tid, r = o >> 4, c = o & 15;
      gload_lds16(Kg + (size_t)(b * 2048 + jc * 64 + r) * 2048 + h * 128 + ((c ^ (r & 15)) * 8),
                  (char*)Ks + o * 16);
    }
    __builtin_amdgcn_s_waitcnt(0);
    __syncthreads();
    #pragma unroll
    for (int kt = 0; kt < 4; ++kt) {
      f32x4 c4 = {0.f, 0.f, 0.f, 0.f};
      #pragma unroll
      for (int ks = 0; ks < 4; ++ks) {
        f16x8 kf = *(const f16x8*)(KsB + (kt * 16 + l16) * 256 + (((ks * 4 + quad) ^ l16) * 16));
        c4 = __builtin_amdgcn_mfma_f32_16x16x32_f16(kf, qf[ks], c4, 0, 0, 0);
      }
      sc[jj][kt] = c4;
    }
  }

  // softmax over keys for query column l16; invalid blocks -> -1e30 (exp -> 0)
  const float scale = 0.08838834764831845f;  // 1/sqrt(128)
  float rmax = -1e30f;
  #pragma unroll
  for (int jj = 0; jj < 5; ++jj) {
    const int j = qb - 2 + jj;
    const bool valid = (j >= 0) && (j < 32);
    #pragma unroll
    for (int kt = 0; kt < 4; ++kt)
      #pragma unroll
      for (int r = 0; r < 4; ++r) {
        float v = valid ? sc[jj][kt][r] * scale : -1e30f;
        sc[jj][kt][r] = v;
        rmax = fmaxf(rmax, v);
      }
  }
  rmax = fmaxf(rmax, __shfl_xor(rmax, 16));
  rmax = fmaxf(rmax, __shfl_xor(rmax, 32));
  float rsum = 0.f;
  #pragma unroll
  for (int jj = 0; jj < 5; ++jj)
    #pragma unroll
    for (int kt = 0; kt < 4; ++kt)
      #pragma unroll
      for (int r = 0; r < 4; ++r) {
        float p = __expf(sc[jj][kt][r] - rmax);
        sc[jj][kt][r] = p;
        rsum += p;
      }
  rsum += __shfl_xor(rsum, 16);
  rsum += __shfl_xor(rsum, 32);
  const float pinv = 1.0f / rsum;

  // PV: O^T = V^T * P^T via 16x16x16 f16 MFMA; P^T fragment == sc registers
  f32x4 oacc[8];
  #pragma unroll
  for (int dt = 0; dt < 8; ++dt) oacc[dt] = (f32x4){0.f, 0.f, 0.f, 0.f};
  #pragma unroll
  for (int jj = 0; jj < 5; ++jj) {
    int j = qb - 2 + jj;
    int jc = j < 0 ? 0 : (j > 31 ? 31 : j);
    __syncthreads();  // protect Vs from previous block's readers
    #pragma unroll
    for (int p = 0; p < 4; ++p) {
      int o = p * 256 + tid, d = o >> 3, c = o & 7;
      gload_lds16(Vtg + (size_t)((b * 16 + h) * 128 + d) * 2048 + jc * 64 + ((c ^ (d & 7)) * 8),
                  (char*)Vs + o * 16);
    }
    __builtin_amdgcn_s_waitcnt(0);
    __syncthreads();
    #pragma unroll
    for (int kt = 0; kt < 4; ++kt) {
      f16x4 pb = { (_Float16)sc[jj][kt][0], (_Float16)sc[jj][kt][1],
                   (_Float16)sc[jj][kt][2], (_Float16)sc[jj][kt][3] };
      #pragma unroll
      for (int dt = 0; dt < 8; ++dt) {
        f16x4 vv = *(const f16x4*)(VsB + (dt * 16 + l16) * 128 +
                                   (((2 * kt + (quad >> 1)) ^ (l16 & 7)) * 16) + (quad & 1) * 8);
        oacc[dt] = __builtin_amdgcn_mfma_f32_16x16x16f16(vv, pb, oacc[dt], 0, 0, 0);
      }
    }
  }
  // O^T C-layout: row d = dt*16 + quad*4 + r, col qrow = l16 -> write O[qrow][d], 8B stores
  const size_t orow = (size_t)(b * 2048 + qb * 64 + w * 16 + l16);
  #pragma unroll
  for (int dt = 0; dt < 8; ++dt) {
    f16x4 ov = { (_Float16)(oacc[dt][0] * pinv), (_Float16)(oacc[dt][1] * pinv),
                 (_Float16)(oacc[dt][2] * pinv), (_Float16)(oacc[dt][3] * pinv) };
    *(f16x4*)(Og + orow * 2048 + h * 128 + dt * 16 + quad * 4) = ov;
  }
}

extern "C" void kernel_launch(void* const* d_in, const int* in_sizes, int n_in,
                              void* d_out, int out_size, void* d_ws, size_t ws_size,
                              hipStream_t stream) {
  const float* Hs = (const float*)d_in[0];
  const float* Wq = (const float*)d_in[1];
  const float* Wk = (const float*)d_in[2];
  const float* Wv = (const float*)d_in[3];
  const float* Wo = (const float*)d_in[4];
  // ws layout (f16 elements): 128 MiB total
  _Float16* Hb  = (_Float16*)d_ws;          // 8388608  : H cast            [4096][2048]
  _Float16* Wt  = Hb  + 8388608;            // 16777216 : Wq/Wk/Wv/Wo^T     4 x [2048][2048]
  _Float16* Qb  = Wt  + 16777216;           // 8388608  : Q  [b*2048+s][h*128+d]
  _Float16* Kb  = Qb  + 8388608;            // 8388608  : K
  _Float16* Vb  = Kb  + 8388608;            // 8388608  : V
  _Float16* Vtb = Vb  + 8388608;            // 8388608  : V^T [(b*16+h)*128+d][s]
  _Float16* Ob  = Vtb + 8388608;            // 8388608  : attn out [b*2048+s][h*128+d]
  float* out = (float*)d_out;

  cast_f32_f16<<<8192, 256, 0, stream>>>(Hs, Hb, 8388608);
  wtrans<<<dim3(32, 32, 4), 256, 0, stream>>>(Wq, Wk, Wv, Wo, Wt);
  gemm_bt<_Float16><<<dim3(16, 32, 3), 256, 0, stream>>>(Hb, Wt, Qb, 2048, 2048,
                                                         (size_t)4194304, (size_t)8388608);
  vtrans<<<dim3(32, 2, 32), 256, 0, stream>>>(Vb, Vtb);
  attn<<<dim3(32, 16, 2), 256, 0, stream>>>(Qb, Kb, Vtb, Ob);
  gemm_bt<float><<<dim3(16, 32, 1), 256, 0, stream>>>(Ob, Wt + 3 * 4194304, out, 2048, 2048,
                                                      (size_t)0, (size_t)0);
}